// Round 3
// baseline (120.238 us; speedup 1.0000x reference)
//
#include <hip/hip_runtime.h>

typedef __attribute__((ext_vector_type(8))) short short8;
typedef __attribute__((ext_vector_type(4))) float f32x4;

#define DIN 512
#define DOUT 128
#define KK 16
#define BTOT 8192
#define KAUG (DIN * KK + DIN)        // 8704 augmented K (spline 8192 + skip 512)
#define BK 64
#define NCHUNK_TOT (KAUG / BK)       // 136 chunks of BK=64
#define NSPL 8                       // split-K factor
#define CPB (NCHUNK_TOT / NSPL)      // 17 chunks per block
#define BM 128                       // b-rows per block
#define CHUNK_BYTES (DOUT * BK * 2)  // 16384: W chunk 128 o x 64 k bf16
#define CBASE 32768                  // C dbuf after W dbuf
#define LDS_BYTES 65536              // W dbuf 32K + C dbuf 32K (static -> 2 blocks/CU)

// round-to-nearest-even fp32 -> bf16
__device__ static inline unsigned short f2bf(float x) {
  unsigned u = __builtin_bit_cast(unsigned, x);
  return (unsigned short)((u + 0x7FFFu + ((u >> 16) & 1u)) >> 16);
}

// async global->LDS, 16B per lane (dst = wave-uniform base, HW adds lane*16)
__device__ static inline void llds16(const char* g, char* l) {
  __builtin_amdgcn_global_load_lds(
      (const __attribute__((address_space(1))) unsigned int*)g,
      (__attribute__((address_space(3))) unsigned int*)l, 16, 0, 0);
}

// ---------------- prep: pack W_aug into swizzled bf16 chunk image ----------------
// W''[g][o][kcs] granules of 16B (8 bf16), kcs = kc ^ (o&7); chunk = 128 o x 64 k.
// content: k = g*64 + kc*8 ..+8 ; k<8192 -> w[o][k] ((o,8192) view); else skip.
__global__ __launch_bounds__(256) void build_wpp(const float* __restrict__ w,
                                                 const float* __restrict__ sk,
                                                 unsigned short* __restrict__ wpp) {
  const int gi = blockIdx.x * 256 + threadIdx.x;  // granule id < 136*1024
  const int g = gi >> 10;
  const int rem = gi & 1023;
  const int o = rem >> 3;
  const int kcs = rem & 7;
  const int kc = kcs ^ (o & 7);
  const int kglob = g * 64 + kc * 8;
  const float* src = (kglob < 8192) ? (w + (size_t)o * 8192 + kglob)
                                    : (sk + (size_t)o * 512 + (kglob - 8192));
  const float4 v0 = ((const float4*)src)[0];
  const float4 v1 = ((const float4*)src)[1];
  uint4 pk;
  pk.x = f2bf(v0.x) | ((unsigned)f2bf(v0.y) << 16);
  pk.y = f2bf(v0.z) | ((unsigned)f2bf(v0.w) << 16);
  pk.z = f2bf(v1.x) | ((unsigned)f2bf(v1.y) << 16);
  pk.w = f2bf(v1.z) | ((unsigned)f2bf(v1.w) << 16);
  ((uint4*)wpp)[gi] = pk;
}

// ---------------- main: 128x128 tile, 4 waves (wave-tile 64x64), 2 blocks/CU ----
// grid 512 = 64 b-tiles x 8 k-splits (2 blocks/CU); block 256 (wave grid 2m x 2n).
// Per chunk: [x prefetch(c+1)] [stage W(c+1)] [16 ds_read + 32 MFMA] [build C(c+1)]
// [barrier]. 16 reads : 32 MFMA (B/MAC 0.0625, was 0.094); barrier drain overlaps
// with the co-resident second block (m114 mechanism).
__global__ __launch_bounds__(256, 2) void kan_mfma(const float* __restrict__ x,
                                                   const unsigned short* __restrict__ wpp,
                                                   const float* __restrict__ bias,
                                                   float* __restrict__ out) {
  __shared__ __align__(16) char smem[LDS_BYTES];
  const int tid = threadIdx.x;
  const int bt = blockIdx.x >> 3;
  const int sp = blockIdx.x & 7;
  const int b0 = bt * BM;
  const int wid = tid >> 6, lane = tid & 63;
  const int lr = lane & 15, lq = lane >> 4;
  const int wm = wid >> 1, wn = wid & 1;   // 2 m-waves x 2 n-waves
  const int g0 = sp * CPB;

  f32x4 acc[4][4] = {};

  // ---- helpers ----
  auto stageW = [&](int g, int buf) {
    const char* gsrc = ((const char*)wpp) + (size_t)g * CHUNK_BYTES + wid * 4096 + lane * 16;
    char* ldst = smem + buf + wid * 4096;
#pragma unroll
    for (int it = 0; it < 4; ++it) llds16(gsrc + it * 1024, ldst + it * 1024);
  };

  // spline C-build: 512 (row, i) pairs (128 rows x 4 dims), 2 per thread.
  // Row = 8 granules of 16B; granule stored at index ^ (row&7). Zero the pair of
  // granules covering this dim's 16 slots, then place the 2 hat coefficients.
  auto buildSpline = [&](int cbuf, float xv0, float xv1) {
#pragma unroll
    for (int hh = 0; hh < 2; ++hh) {
      const int bl = (tid >> 2) + hh * 64;   // row 0..127
      const int il = tid & 3;                // dim-in-chunk 0..3
      const float xv = hh ? xv1 : xv0;
      float t = fminf(fmaxf((xv + 3.0f) * (1.0f / 6.0f), 0.0f), 1.0f);
      const float pos = t * 15.0f;
      int i0 = (int)pos;
      i0 = i0 > 14 ? 14 : i0;
      const float f = pos - (float)i0;
      char* row = smem + cbuf + bl * 128;
      const int swz = bl & 7;
      char* gA = row + (((il * 2) ^ swz) << 4);
      char* gB = row + (((il * 2 + 1) ^ swz) << 4);
      *(uint4*)gA = make_uint4(0, 0, 0, 0);
      *(uint4*)gB = make_uint4(0, 0, 0, 0);
      const unsigned short h0 = f2bf(1.0f - f);
      const unsigned short h1 = f2bf(f);
      const int i1 = i0 + 1;  // i0<=14 -> i1<=15
      *(unsigned short*)(((i0 & 8) ? gB : gA) + (i0 & 7) * 2) = h0;
      *(unsigned short*)(((i1 & 8) ? gB : gA) + (i1 & 7) * 2) = h1;
    }
  };

  // skip-augmented C-build: raw x in bf16; 128 rows x 8 granules, 4 per thread
  auto buildSkip = [&](int g, int cbuf) {
    const int ioff = (g - 128) * BK;
    const int bl = tid >> 1, q = tid & 1;
    const float* xr = x + (size_t)(b0 + bl) * DIN + ioff;
    char* row = smem + cbuf + bl * 128;
    const int swz = bl & 7;
#pragma unroll
    for (int gg = 0; gg < 4; ++gg) {
      const int kc = q * 4 + gg;
      const float4 v0 = ((const float4*)(xr + kc * 8))[0];
      const float4 v1 = ((const float4*)(xr + kc * 8))[1];
      uint4 pk;
      pk.x = f2bf(v0.x) | ((unsigned)f2bf(v0.y) << 16);
      pk.y = f2bf(v0.z) | ((unsigned)f2bf(v0.w) << 16);
      pk.z = f2bf(v1.x) | ((unsigned)f2bf(v1.y) << 16);
      pk.w = f2bf(v1.z) | ((unsigned)f2bf(v1.w) << 16);
      *(uint4*)(row + ((kc ^ swz) << 4)) = pk;
    }
  };

  // x scalars feeding buildSpline for chunk g (rows 0-63 via a, 64-127 via b)
  auto loadX = [&](int g, float& a, float& b) {
    const int r0 = tid >> 2, il = tid & 3;
    a = x[(size_t)(b0 + r0) * DIN + g * 4 + il];
    b = x[(size_t)(b0 + 64 + r0) * DIN + g * 4 + il];
  };

  // ---- prologue: chunk 0 into parity-0 buffers (g0 <= 119 -> always spline) ----
  stageW(g0, 0);
  {
    float a, b;
    loadX(g0, a, b);
    buildSpline(CBASE + 0, a, b);
  }
  __syncthreads();

  // ---- main loop ----
  for (int c = 0; c < CPB; ++c) {
    const int g = g0 + c;
    const int pb = (c & 1) << 14;       // 0 / 16384 parity
    const int nb = pb ^ 16384;
    const bool haveNext = (c + 1 < CPB);
    const int gn = g + 1;

    float xn0 = 0.0f, xn1 = 0.0f;
    if (haveNext && gn < 128) loadX(gn, xn0, xn1);  // issue early, consume late
    if (haveNext) stageW(gn, nb);                   // in flight across MFMA phase

    // ---- MFMA: 2 K32-steps from parity-pb buffers; 8 reads : 16 MFMA per step --
    const char* Wb = smem + pb;
    const char* Cb = smem + CBASE + pb;
#pragma unroll
    for (int ks = 0; ks < 2; ++ks) {
      const int gq = ks * 4 + lq;
      short8 af[4], bfr[4];
#pragma unroll
      for (int mt = 0; mt < 4; ++mt) {
        const int m = wm * 64 + mt * 16 + lr;
        af[mt] = *(const short8*)(Cb + m * 128 + ((gq ^ (m & 7)) << 4));
      }
#pragma unroll
      for (int nt = 0; nt < 4; ++nt) {
        const int o = wn * 64 + nt * 16 + lr;
        bfr[nt] = *(const short8*)(Wb + o * 128 + ((gq ^ (o & 7)) << 4));
      }
#pragma unroll
      for (int mt = 0; mt < 4; ++mt)
#pragma unroll
        for (int nt = 0; nt < 4; ++nt)
          acc[mt][nt] = __builtin_amdgcn_mfma_f32_16x16x32_bf16(af[mt], bfr[nt], acc[mt][nt], 0, 0, 0);
    }

    // ---- build C(c+1) into the other parity (its readers finished at the
    //      barrier that ended chunk c-1) ----
    if (haveNext) {
      if (gn < 128) buildSpline(CBASE + nb, xn0, xn1);
      else buildSkip(gn, CBASE + nb);
    }
    __syncthreads();  // drains stage(c+1) (issued a full MFMA phase ago) + C writes
  }

  // ---- epilogue: atomic accumulate across k-splits; bias on split 0 ----
#pragma unroll
  for (int nt = 0; nt < 4; ++nt) {
    const int col = wn * 64 + nt * 16 + lr;
    const float bv = (sp == 0) ? bias[col] : 0.0f;
#pragma unroll
    for (int mt = 0; mt < 4; ++mt) {
      const int rowb = b0 + wm * 64 + mt * 16 + lq * 4;
#pragma unroll
      for (int r = 0; r < 4; ++r)
        atomicAdd(out + (size_t)(rowb + r) * DOUT + col, acc[mt][nt][r] + bv);
    }
  }
}

// ---------------- safety-net naive kernel (only if ws too small) ----------------
__global__ void kan_naive(const float* __restrict__ x, const float* __restrict__ w,
                          const float* __restrict__ skw, const float* __restrict__ bias,
                          float* __restrict__ out) {
  const int b = blockIdx.x;
  const int o = threadIdx.x;
  float acc = bias[o];
  for (int i = 0; i < DIN; ++i) {
    float xv = x[(size_t)b * DIN + i];
    float t = fminf(fmaxf((xv + 3.0f) * (1.0f / 6.0f), 0.0f), 1.0f);
    float p = t * 15.0f;
    float fi = floorf(p);
    int i0 = (int)fi;
    int i1 = (i0 < 15) ? i0 + 1 : 15;
    float f = p - fi;
    const float* wr = &w[((size_t)o * DIN + i) * KK];
    acc += (1.0f - f) * wr[i0] + f * wr[i1] + xv * skw[(size_t)o * DIN + i];
  }
  out[(size_t)b * DOUT + o] = acc;
}

extern "C" void kernel_launch(void* const* d_in, const int* in_sizes, int n_in,
                              void* d_out, int out_size, void* d_ws, size_t ws_size,
                              hipStream_t stream) {
  const float* x    = (const float*)d_in[0];
  const float* w    = (const float*)d_in[1];  // (128, 512, 16) fp32
  const float* skw  = (const float*)d_in[2];  // (128, 512) fp32
  const float* bias = (const float*)d_in[3];  // (128,) fp32
  float* out = (float*)d_out;                 // (8192, 128) fp32

  const size_t need = (size_t)NCHUNK_TOT * CHUNK_BYTES;  // 2,228,224 B
  if (ws_size < need) {
    kan_naive<<<BTOT, DOUT, 0, stream>>>(x, w, skw, bias, out);
    return;
  }

  unsigned short* wpp = (unsigned short*)d_ws;

  hipMemsetAsync(d_out, 0, (size_t)out_size * sizeof(float), stream);
  build_wpp<<<NCHUNK_TOT * 1024 / 256, 256, 0, stream>>>(w, skw, wpp);
  kan_mfma<<<(BTOT / BM) * NSPL, 256, 0, stream>>>(x, wpp, bias, out);
}